// Round 2
// baseline (504.462 us; speedup 1.0000x reference)
//
#include <hip/hip_runtime.h>
#include <hip/hip_bf16.h>
#include <stdint.h>

#define B_ROWS 4096
#define IN_F   4096
#define OUT_F  4096

#define BM 128
#define BN 128
#define BK 32

typedef float  f32x4  __attribute__((ext_vector_type(4)));
typedef short  bf16x8 __attribute__((ext_vector_type(8)));

#define AS1 __attribute__((address_space(1)))
#define AS3 __attribute__((address_space(3)))

__device__ __forceinline__ uint16_t f2bf_rne(float f) {
    uint32_t u = __float_as_uint(f);
    uint32_t r = u + 0x7fffu + ((u >> 16) & 1u);
    return (uint16_t)(r >> 16);
}

// x fp32 -> bf16 (4 elems/thread, float4 in, ushort4 out)
__global__ void cvt_x_kernel(const float* __restrict__ x, uint16_t* __restrict__ xb) {
    int i = (blockIdx.x * 256 + threadIdx.x) * 4;
    float4 v = *(const float4*)(x + i);
    ushort4 o;
    o.x = f2bf_rne(v.x); o.y = f2bf_rne(v.y);
    o.z = f2bf_rne(v.z); o.w = f2bf_rne(v.w);
    *(ushort4*)(xb + i) = o;
}

// Sniff mask dtype: int32 0/1 mask -> all upper 3 bytes of every word are 0.
// Byte-packed bool mask -> 1s appear in upper byte lanes (P(miss) ~ 0.9^49152 ~ 0).
// flag = 1 -> byte mask, flag = 0 -> int32 mask.
__global__ void detect_mask_kernel(const uint32_t* __restrict__ mraw, int* __restrict__ flag) {
    __shared__ uint32_t red[256];
    uint32_t acc = 0;
    for (int k = threadIdx.x; k < 16384; k += 256) acc |= mraw[k];
    red[threadIdx.x] = acc;
    __syncthreads();
    for (int s = 128; s > 0; s >>= 1) {
        if (threadIdx.x < s) red[threadIdx.x] |= red[threadIdx.x + s];
        __syncthreads();
    }
    if (threadIdx.x == 0) *flag = (red[0] & 0xFFFFFF00u) ? 1 : 0;
}

// w fp32 + mask (dtype per *flag) -> masked bf16
__global__ void cvt_w_kernel(const float* __restrict__ w, const void* __restrict__ mraw,
                             const int* __restrict__ flag, uint16_t* __restrict__ wb) {
    int i = (blockIdx.x * 256 + threadIdx.x) * 4;
    float4 v = *(const float4*)(w + i);
    int m0, m1, m2, m3;
    if (*flag) {   // 1-byte bool mask
        uchar4 mm = *(const uchar4*)((const uint8_t*)mraw + i);
        m0 = mm.x; m1 = mm.y; m2 = mm.z; m3 = mm.w;
    } else {       // int32 0/1 mask
        int4 mm = *(const int4*)((const int*)mraw + i);
        m0 = mm.x; m1 = mm.y; m2 = mm.z; m3 = mm.w;
    }
    ushort4 o;
    o.x = m0 ? f2bf_rne(v.x) : (uint16_t)0;
    o.y = m1 ? f2bf_rne(v.y) : (uint16_t)0;
    o.z = m2 ? f2bf_rne(v.z) : (uint16_t)0;
    o.w = m3 ? f2bf_rne(v.w) : (uint16_t)0;
    *(ushort4*)(wb + i) = o;
}

// C[b,o] = relu( sum_k xb[b,k]*wb[o,k] + bias[o] ) + x[b, rc[o]]
// m97-style: 128x128 tile, BK=32, 4 waves (2x2), each wave 64x64 via 4x4 MFMA 16x16x32
__global__ __launch_bounds__(256) void gemm_kernel(
    const uint16_t* __restrict__ xb, const uint16_t* __restrict__ wb,
    const float* __restrict__ x, const float* __restrict__ bias,
    const int* __restrict__ rc, float* __restrict__ out)
{
    __shared__ alignas(16) uint16_t As[BM * BK];   // 8 KB, row-major [128][32]
    __shared__ alignas(16) uint16_t Bs[BN * BK];   // 8 KB
    __shared__ float bias_s[BN];
    __shared__ int   rc_s[BN];

    const int tid  = threadIdx.x;
    const int row0 = blockIdx.y * BM;
    const int col0 = blockIdx.x * BN;

    if (tid < BN) { bias_s[tid] = bias[col0 + tid]; rc_s[tid] = rc[col0 + tid]; }

    const int wave = tid >> 6, lane = tid & 63;
    const int wm = wave >> 1, wn = wave & 1;
    const int quad = lane >> 4, l16 = lane & 15;

    f32x4 acc[4][4];
#pragma unroll
    for (int i = 0; i < 4; ++i)
#pragma unroll
        for (int j = 0; j < 4; ++j)
            acc[i][j] = (f32x4){0.f, 0.f, 0.f, 0.f};

    for (int k0 = 0; k0 < IN_F; k0 += BK) {
        // stage 128x32 bf16 tiles of A and B via async global->LDS, 16B/lane.
        // chunk c = tid + it*256; LDS byte offset = c*16 -> wave-uniform base + lane*16.
#pragma unroll
        for (int it = 0; it < 2; ++it) {
            int c  = tid + it * 256;
            int r  = c >> 2;            // 0..127
            int kc = (c & 3) * 8;       // 0,8,16,24
            __builtin_amdgcn_global_load_lds(
                (const AS1 void*)(xb + (size_t)(row0 + r) * IN_F + k0 + kc),
                (AS3 void*)(As + c * 8), 16, 0, 0);
            __builtin_amdgcn_global_load_lds(
                (const AS1 void*)(wb + (size_t)(col0 + r) * IN_F + k0 + kc),
                (AS3 void*)(Bs + c * 8), 16, 0, 0);
        }
        __syncthreads();   // compiler drains vmcnt before s_barrier

        // A-operand layout: lane holds A[m = lane&15][k = quad*8 + j], contiguous 16B
        bf16x8 af[4], bfr[4];
#pragma unroll
        for (int i = 0; i < 4; ++i)
            af[i] = *(const bf16x8*)(As + (wm * 64 + i * 16 + l16) * BK + quad * 8);
#pragma unroll
        for (int j = 0; j < 4; ++j)
            bfr[j] = *(const bf16x8*)(Bs + (wn * 64 + j * 16 + l16) * BK + quad * 8);

#pragma unroll
        for (int i = 0; i < 4; ++i)
#pragma unroll
            for (int j = 0; j < 4; ++j)
                acc[i][j] = __builtin_amdgcn_mfma_f32_16x16x32_bf16(af[i], bfr[j], acc[i][j], 0, 0, 0);
        __syncthreads();
    }

    // Epilogue: C/D layout col = lane&15, row = quad*4 + reg  (m89-verified)
#pragma unroll
    for (int i = 0; i < 4; ++i) {
        const int grow0 = row0 + wm * 64 + i * 16 + quad * 4;
#pragma unroll
        for (int j = 0; j < 4; ++j) {
            const int lcol = wn * 64 + j * 16 + l16;
            const int gcol = col0 + lcol;
            const float bv = bias_s[lcol];
            const int   rv = rc_s[lcol];
#pragma unroll
            for (int r = 0; r < 4; ++r) {
                const int grow = grow0 + r;
                float v = acc[i][j][r] + bv;
                v = fmaxf(v, 0.0f);
                v += x[(size_t)grow * IN_F + rv];   // fp32 residual gather
                out[(size_t)grow * OUT_F + gcol] = v;
            }
        }
    }
}

extern "C" void kernel_launch(void* const* d_in, const int* in_sizes, int n_in,
                              void* d_out, int out_size, void* d_ws, size_t ws_size,
                              hipStream_t stream) {
    const float* x    = (const float*)d_in[0];
    const float* w    = (const float*)d_in[1];
    const float* bias = (const float*)d_in[2];
    const void*  mask = (const void*)d_in[3];
    const int*   rc   = (const int*)d_in[4];
    float* out = (float*)d_out;

    uint16_t* xb   = (uint16_t*)d_ws;                     // 32 MB
    uint16_t* wb   = xb + (size_t)B_ROWS * IN_F;          // 32 MB
    int*      flag = (int*)(wb + (size_t)OUT_F * IN_F);   // 4 B

    detect_mask_kernel<<<1, 256, 0, stream>>>((const uint32_t*)mask, flag);
    cvt_x_kernel<<<(B_ROWS * IN_F) / (256 * 4), 256, 0, stream>>>(x, xb);
    cvt_w_kernel<<<(OUT_F * IN_F) / (256 * 4), 256, 0, stream>>>(w, mask, flag, wb);

    dim3 grid(OUT_F / BN, B_ROWS / BM);
    gemm_kernel<<<grid, 256, 0, stream>>>(xb, wb, x, bias, rc, out);
}

// Round 3
// 412.802 us; speedup vs baseline: 1.2220x; 1.2220x over previous
//
#include <hip/hip_runtime.h>
#include <hip/hip_bf16.h>
#include <stdint.h>

#define B_ROWS 4096
#define IN_F   4096
#define OUT_F  4096

#define BM 128
#define BN 128
#define BK 32

typedef float  f32x4  __attribute__((ext_vector_type(4)));
typedef short  bf16x8 __attribute__((ext_vector_type(8)));
typedef unsigned short u16x4 __attribute__((ext_vector_type(4)));

#define AS1 __attribute__((address_space(1)))
#define AS3 __attribute__((address_space(3)))

__device__ __forceinline__ uint16_t f2bf_rne(float f) {
    uint32_t u = __float_as_uint(f);
    uint32_t r = u + 0x7fffu + ((u >> 16) & 1u);
    return (uint16_t)(r >> 16);
}
__device__ __forceinline__ float bf2f(uint16_t h) {
    return __uint_as_float(((uint32_t)h) << 16);
}

// Fused: x fp32 -> xb (bf16, row-major [b][k]) and xbT (bf16, transposed [k][b]).
// 64x64 tiles, LDS staging with +1 padding for the transpose.
__global__ __launch_bounds__(256) void cvt_x_t_kernel(
    const float* __restrict__ x, uint16_t* __restrict__ xb, uint16_t* __restrict__ xbT)
{
    __shared__ float t[64][65];
    const int r0 = blockIdx.y * 64;   // batch rows
    const int c0 = blockIdx.x * 64;   // feature cols
    const int tid = threadIdx.x;
    const int lr = tid >> 4;          // 0..15
    const int lc4 = (tid & 15) * 4;   // 0..60

#pragma unroll
    for (int p = 0; p < 4; ++p) {
        const int row = p * 16 + lr;
        float4 v = *(const float4*)(x + (size_t)(r0 + row) * IN_F + c0 + lc4);
        ushort4 o;
        o.x = f2bf_rne(v.x); o.y = f2bf_rne(v.y);
        o.z = f2bf_rne(v.z); o.w = f2bf_rne(v.w);
        *(ushort4*)(xb + (size_t)(r0 + row) * IN_F + c0 + lc4) = o;
        t[row][lc4 + 0] = v.x; t[row][lc4 + 1] = v.y;
        t[row][lc4 + 2] = v.z; t[row][lc4 + 3] = v.w;
    }
    __syncthreads();
#pragma unroll
    for (int p = 0; p < 4; ++p) {
        const int c = p * 16 + lr;    // source col -> dest row
        ushort4 o;
        o.x = f2bf_rne(t[lc4 + 0][c]);
        o.y = f2bf_rne(t[lc4 + 1][c]);
        o.z = f2bf_rne(t[lc4 + 2][c]);
        o.w = f2bf_rne(t[lc4 + 3][c]);
        *(ushort4*)(xbT + (size_t)(c0 + c) * B_ROWS + r0 + lc4) = o;
    }
}

// Sniff mask dtype over 1024 words (4 KB - within bounds for both dtypes).
// int32 0/1 mask -> upper 3 bytes of every word are 0.
// byte mask -> some upper byte is 1 w.p. 1 - 0.729^1024 ~ 1.
__global__ void detect_mask_kernel(const uint32_t* __restrict__ mraw, int* __restrict__ flag) {
    __shared__ uint32_t red[256];
    uint32_t acc = 0;
    for (int k = threadIdx.x; k < 1024; k += 256) acc |= mraw[k];
    red[threadIdx.x] = acc;
    __syncthreads();
    for (int s = 128; s > 0; s >>= 1) {
        if (threadIdx.x < s) red[threadIdx.x] |= red[threadIdx.x + s];
        __syncthreads();
    }
    if (threadIdx.x == 0) *flag = (red[0] & 0xFFFFFF00u) ? 1 : 0;
}

// w fp32 + mask (dtype per *flag) -> masked bf16
__global__ void cvt_w_kernel(const float* __restrict__ w, const void* __restrict__ mraw,
                             const int* __restrict__ flag, uint16_t* __restrict__ wb) {
    int i = (blockIdx.x * 256 + threadIdx.x) * 4;
    float4 v = *(const float4*)(w + i);
    int m0, m1, m2, m3;
    if (*flag) {   // 1-byte bool mask
        uchar4 mm = *(const uchar4*)((const uint8_t*)mraw + i);
        m0 = mm.x; m1 = mm.y; m2 = mm.z; m3 = mm.w;
    } else {       // int32 0/1 mask
        int4 mm = *(const int4*)((const int*)mraw + i);
        m0 = mm.x; m1 = mm.y; m2 = mm.z; m3 = mm.w;
    }
    ushort4 o;
    o.x = m0 ? f2bf_rne(v.x) : (uint16_t)0;
    o.y = m1 ? f2bf_rne(v.y) : (uint16_t)0;
    o.z = m2 ? f2bf_rne(v.z) : (uint16_t)0;
    o.w = m3 ? f2bf_rne(v.w) : (uint16_t)0;
    *(ushort4*)(wb + i) = o;
}

// C[b,o] = relu( sum_k xb[b,k]*wb[o,k] + bias[o] ) + xbT[rc[o]][b]
__global__ __launch_bounds__(256) void gemm_kernel(
    const uint16_t* __restrict__ xb, const uint16_t* __restrict__ wb,
    const uint16_t* __restrict__ xbT, const float* __restrict__ bias,
    const int* __restrict__ rc, float* __restrict__ out)
{
    __shared__ alignas(16) uint16_t As[BM * BK];   // 8 KB, row-major [128][32]
    __shared__ alignas(16) uint16_t Bs[BN * BK];   // 8 KB
    __shared__ float bias_s[BN];
    __shared__ int   rc_s[BN];

    const int tid  = threadIdx.x;
    const int row0 = blockIdx.y * BM;
    const int col0 = blockIdx.x * BN;

    if (tid < BN) { bias_s[tid] = bias[col0 + tid]; rc_s[tid] = rc[col0 + tid]; }

    const int wave = tid >> 6, lane = tid & 63;
    const int wm = wave >> 1, wn = wave & 1;
    const int quad = lane >> 4, l16 = lane & 15;

    f32x4 acc[4][4];
#pragma unroll
    for (int i = 0; i < 4; ++i)
#pragma unroll
        for (int j = 0; j < 4; ++j)
            acc[i][j] = (f32x4){0.f, 0.f, 0.f, 0.f};

    for (int k0 = 0; k0 < IN_F; k0 += BK) {
        // stage 128x32 bf16 tiles via async global->LDS, 16B/lane, wave-uniform base.
#pragma unroll
        for (int it = 0; it < 2; ++it) {
            int c  = tid + it * 256;
            int r  = c >> 2;            // 0..127
            int kc = (c & 3) * 8;       // 0,8,16,24
            __builtin_amdgcn_global_load_lds(
                (const AS1 void*)(xb + (size_t)(row0 + r) * IN_F + k0 + kc),
                (AS3 void*)(As + c * 8), 16, 0, 0);
            __builtin_amdgcn_global_load_lds(
                (const AS1 void*)(wb + (size_t)(col0 + r) * IN_F + k0 + kc),
                (AS3 void*)(Bs + c * 8), 16, 0, 0);
        }
        __syncthreads();

        // A-operand layout: lane holds A[m = lane&15][k = quad*8 + j]
        bf16x8 af[4], bfr[4];
#pragma unroll
        for (int i = 0; i < 4; ++i)
            af[i] = *(const bf16x8*)(As + (wm * 64 + i * 16 + l16) * BK + quad * 8);
#pragma unroll
        for (int j = 0; j < 4; ++j)
            bfr[j] = *(const bf16x8*)(Bs + (wn * 64 + j * 16 + l16) * BK + quad * 8);

#pragma unroll
        for (int i = 0; i < 4; ++i)
#pragma unroll
            for (int j = 0; j < 4; ++j)
                acc[i][j] = __builtin_amdgcn_mfma_f32_16x16x32_bf16(af[i], bfr[j], acc[i][j], 0, 0, 0);
        __syncthreads();
    }

    // Epilogue. C/D layout: col = lane&15, row = quad*4 + reg (m89-verified).
    // Residual via xbT: per (j,i) an 8B contiguous load; the 4 quads of a wave
    // cover a full 64B line of xbT[rv].
#pragma unroll
    for (int j = 0; j < 4; ++j) {
        const int lcol = wn * 64 + j * 16 + l16;
        const int gcol = col0 + lcol;
        const float bv = bias_s[lcol];
        const int   rv = rc_s[lcol];
#pragma unroll
        for (int i = 0; i < 4; ++i) {
            const int grow0 = row0 + wm * 64 + i * 16 + quad * 4;
            u16x4 xq = *(const u16x4*)(xbT + (size_t)rv * B_ROWS + grow0);
#pragma unroll
            for (int r = 0; r < 4; ++r) {
                float v = fmaxf(acc[i][j][r] + bv, 0.0f) + bf2f(xq[r]);
                out[(size_t)(grow0 + r) * OUT_F + gcol] = v;
            }
        }
    }
}

extern "C" void kernel_launch(void* const* d_in, const int* in_sizes, int n_in,
                              void* d_out, int out_size, void* d_ws, size_t ws_size,
                              hipStream_t stream) {
    const float* x    = (const float*)d_in[0];
    const float* w    = (const float*)d_in[1];
    const float* bias = (const float*)d_in[2];
    const void*  mask = (const void*)d_in[3];
    const int*   rc   = (const int*)d_in[4];
    float* out = (float*)d_out;

    uint16_t* xb   = (uint16_t*)d_ws;                      // 32 MB
    uint16_t* wb   = xb  + (size_t)B_ROWS * IN_F;          // 32 MB
    uint16_t* xbT  = wb  + (size_t)OUT_F * IN_F;           // 32 MB
    int*      flag = (int*)(xbT + (size_t)IN_F * B_ROWS);  // 4 B

    detect_mask_kernel<<<1, 256, 0, stream>>>((const uint32_t*)mask, flag);
    {
        dim3 g(IN_F / 64, B_ROWS / 64);
        cvt_x_t_kernel<<<g, 256, 0, stream>>>(x, xb, xbT);
    }
    cvt_w_kernel<<<(OUT_F * IN_F) / (256 * 4), 256, 0, stream>>>(w, mask, flag, wb);

    dim3 grid(OUT_F / BN, B_ROWS / BM);
    gemm_kernel<<<grid, 256, 0, stream>>>(xb, wb, xbT, bias, rc, out);
}